// Round 2
// 3034.106 us; speedup vs baseline: 1.4177x; 1.4177x over previous
//
#include <hip/hip_runtime.h>

// ---------------- common helpers ----------------

typedef __attribute__((ext_vector_type(8))) short bf16x8;   // 8 bf16 = 4 VGPRs
typedef __attribute__((ext_vector_type(4))) float f32x4;

__device__ __forceinline__ unsigned short f2b(float f) {
  union { float f; unsigned int u; } v; v.f = f;
  unsigned int r = v.u + 0x7FFFu + ((v.u >> 16) & 1u);  // RNE
  return (unsigned short)(r >> 16);
}
__device__ __forceinline__ float b2f(unsigned short h) {
  union { unsigned int u; float f; } v; v.u = ((unsigned int)h) << 16;
  return v.f;
}

#define GLB(p) ((const __attribute__((address_space(1))) void*)(p))
#define LDS(p) ((__attribute__((address_space(3))) void*)(p))

// dims
#define MTOK 8192
#define DIMD 4096
#define HIDD 11008
#define KP1  4160   // 4096 + 64 (xa_up in cols 4096..4103, xa_gate in 4104..4111)
#define KP2  11072  // 11008 + 64 (ha_down in cols 11008..11015)

// ---------------- kernel 1: build augmented X (bf16) ----------------
__global__ __launch_bounds__(256) void build_xaug(
    const float* __restrict__ x, const float* __restrict__ tw,
    const float* __restrict__ a_up, const float* __restrict__ a_gate,
    unsigned short* __restrict__ Xa) {
  const int m = blockIdx.x, t = threadIdx.x;
  const float* xrow = x + (size_t)m * DIMD;
  float du[8] = {0,0,0,0,0,0,0,0}, dg[8] = {0,0,0,0,0,0,0,0};
  for (int k = t; k < DIMD; k += 256) {
    float xv = xrow[k];
    const float* au = a_up + (size_t)k * 8;
    const float* ag = a_gate + (size_t)k * 8;
#pragma unroll
    for (int r = 0; r < 8; r++) { du[r] += xv * au[r]; dg[r] += xv * ag[r]; }
  }
#pragma unroll
  for (int r = 0; r < 8; r++) {
    for (int off = 32; off; off >>= 1) {
      du[r] += __shfl_down(du[r], off, 64);
      dg[r] += __shfl_down(dg[r], off, 64);
    }
  }
  __shared__ float red[4][16];
  __shared__ float xau[16];
  const int wave = t >> 6, lane = t & 63;
  if (lane == 0) {
#pragma unroll
    for (int r = 0; r < 8; r++) { red[wave][r] = du[r]; red[wave][8 + r] = dg[r]; }
  }
  __syncthreads();
  if (t < 16) {
    float s = red[0][t] + red[1][t] + red[2][t] + red[3][t];
    xau[t] = s * 4.0f * tw[m * 3 + (t < 8 ? 0 : 1)];
  }
  __syncthreads();
  unsigned short* dst = Xa + (size_t)m * KP1;
  for (int c = t; c < DIMD; c += 256) dst[c] = f2b(xrow[c]);
  if (t < 64) dst[DIMD + t] = (t < 16) ? f2b(xau[t]) : (unsigned short)0;
}

// ---------------- kernel 2: build augmented transposed weight (bf16) ----------------
__global__ __launch_bounds__(256) void build_baug(
    const float* __restrict__ W, const float* __restrict__ LB,
    unsigned short* __restrict__ BT, int N, int Kmain, int kla, int KP) {
  const int k0 = blockIdx.x * 64;
  const int n0 = blockIdx.y * 64;
  const int t = threadIdx.x;
  const int c = t & 63, r4 = t >> 6;
  if (k0 < Kmain) {
    __shared__ unsigned short tile[64][66];
#pragma unroll
    for (int i = 0; i < 16; i++) {
      int kk = r4 + i * 4;
      tile[kk][c] = f2b(W[(size_t)(k0 + kk) * N + n0 + c]);
    }
    __syncthreads();
#pragma unroll
    for (int i = 0; i < 16; i++) {
      int nn = r4 + i * 4;
      BT[(size_t)(n0 + nn) * KP + k0 + c] = tile[c][nn];
    }
  } else {
    const int lr = k0 + c - kla;
#pragma unroll
    for (int i = 0; i < 16; i++) {
      int nn = r4 + i * 4;
      float v = (lr >= 0 && lr < 8) ? LB[(size_t)lr * N + n0 + nn] : 0.0f;
      BT[(size_t)(n0 + nn) * KP + k0 + c] = f2b(v);
    }
  }
}

// ---------------- kernel 3: lora-down xa into H_aug extra cols ----------------
__global__ __launch_bounds__(256) void lora_down_k(
    unsigned short* __restrict__ H, const float* __restrict__ a_down,
    const float* __restrict__ tw) {
  const int m = blockIdx.x, t = threadIdx.x;
  unsigned short* hrow = H + (size_t)m * KP2;
  float d[8] = {0,0,0,0,0,0,0,0};
  for (int k = t; k < HIDD; k += 256) {
    float hv = b2f(hrow[k]);
    const float* ad = a_down + (size_t)k * 8;
#pragma unroll
    for (int r = 0; r < 8; r++) d[r] += hv * ad[r];
  }
#pragma unroll
  for (int r = 0; r < 8; r++)
    for (int off = 32; off; off >>= 1) d[r] += __shfl_down(d[r], off, 64);
  __shared__ float red[4][8];
  const int wave = t >> 6, lane = t & 63;
  if (lane == 0) {
#pragma unroll
    for (int r = 0; r < 8; r++) red[wave][r] = d[r];
  }
  __syncthreads();
  if (t < 64) {
    float v = 0.0f;
    if (t < 8) v = (red[0][t] + red[1][t] + red[2][t] + red[3][t]) * 4.0f * tw[m * 3 + 2];
    hrow[HIDD + t] = (t < 8) ? f2b(v) : (unsigned short)0;
  }
}

// ---------------- kernel 4: bf16 MFMA GEMM, 256x256 tile, 4-slot ring ----------------
// C = A[M,K](row-major bf16) @ B (given as BT[N,K] row-major bf16)
// BK=32, 8 waves (2M x 4N, per-wave 128x64 via 8x4 MFMA 16x16x32).
// LDS: 4 ring slots x (A 256x32 + B 256x32) bf16 = 128 KB, 1 block/CU.
// Pipeline: counted vmcnt(8) (2 tiles in flight past the landing one), one raw
// s_barrier/iter, stage tile t+3 into slot freed by tile t-1.
// Race-freedom: sched_barrier(0) at loop end pins iter-t MFMAs (and their
// lgkmcnt waits) BEFORE barrier B(t+1) => all reads of the reuse slot have
// COMPLETED before any wave's post-barrier overwrite is issued.
// LDS swizzle: LDS[row][g] = global[row][g ^ ((row>>1)&3)] (pre-swizzled global
// source, linear global_load_lds dest, XOR on the ds_read address) -> every
// bank gets exactly 8 accesses per wave ds_read_b128 = zero conflict overhead.
// MODE 0: store bf16 C into H        [up proj]
// MODE 1: h = silu(C) * H[..]; store [gate proj + swiglu]
// MODE 2: store fp32 C into Out      [down proj]
template <int MODE>
__global__ __launch_bounds__(512) void gemm_ring(
    const unsigned short* __restrict__ A, const unsigned short* __restrict__ BT,
    unsigned short* __restrict__ H, float* __restrict__ Out,
    int K, int lda, int ldb, int ldh) {
  __shared__ alignas(16) unsigned short smem[4 * 16384];  // 128 KB

  const int tid = threadIdx.x;
  const int wave = tid >> 6;
  const int lane = tid & 63;
  const int l16 = lane & 15;
  const int quad = lane >> 4;
  const int wm = wave >> 2;   // 0..1 -> M half
  const int wn = wave & 3;    // 0..3 -> N quarter
  const int wr = wm * 128;
  const int wc = wn * 64;

  // ---- rasterization: bijective XCD chunking (m204) + 8-row stripes, bx-major ----
  const int nbx = gridDim.x, nby = gridDim.y;
  const int nwg = nbx * nby;
  const int rawf = blockIdx.y * nbx + blockIdx.x;
  const int qq = nwg >> 3, rr = nwg & 7;
  const int xcd = rawf & 7, seq = rawf >> 3;
  const int f = (xcd < rr ? xcd * (qq + 1) : rr * (qq + 1) + (xcd - rr) * qq) + seq;
  const int denom = nbx << 3;          // nby % 8 == 0 always here
  const int stripe = f / denom;
  const int rem2 = f - stripe * denom;
  const int bx = rem2 >> 3;
  const int by = (stripe << 3) + (rem2 & 7);
  const int m0 = by * 256;
  const int n0 = bx * 256;

  // ---- staging: thread tid loads 16B; LDS dest linear (wave-uniform base + lane*16).
  // source granule pre-swizzled: g_src = (tid&3) ^ ((tid>>3)&3) == (l&3) ^ ((row_w>>1)&3)
  const int srow = tid >> 2;                                   // 0..127 (+128 for 2nd)
  const int sg = (((tid & 3) ^ ((tid >> 3) & 3)) << 3);        // source element offset
  const unsigned short* gA = A + (size_t)(m0 + srow) * lda + sg;
  const unsigned short* gB = BT + (size_t)(n0 + srow) * ldb + sg;
  const size_t aStep = (size_t)128 * lda;
  const size_t bStep = (size_t)128 * ldb;

  // ---- read offsets (in shorts; row = 32 shorts = 64 B) ----
  const int xorg = (l16 >> 1) & 3;
  const int gsh = ((quad ^ xorg) << 3);
  const int aoff = (wr + l16) * 32 + gsh;
  const int boff = (wc + l16) * 32 + gsh;

  f32x4 acc[8][4];
#pragma unroll
  for (int mi = 0; mi < 8; mi++)
#pragma unroll
    for (int ni = 0; ni < 4; ni++) acc[mi][ni] = f32x4{0.f, 0.f, 0.f, 0.f};

  const int NT = K >> 5;  // BK=32 tiles; K multiple of 64 -> NT even, NT >= 4

#define STAGE_T(slot) do {                                                        \
    unsigned short* lb = smem + ((slot) << 14) + (wave << 9);                     \
    __builtin_amdgcn_global_load_lds(GLB(gA), LDS(lb), 16, 0, 0);                 \
    __builtin_amdgcn_global_load_lds(GLB(gA + aStep), LDS(lb + 4096), 16, 0, 0);  \
    __builtin_amdgcn_global_load_lds(GLB(gB), LDS(lb + 8192), 16, 0, 0);          \
    __builtin_amdgcn_global_load_lds(GLB(gB + bStep), LDS(lb + 12288), 16, 0, 0); \
    gA += 32; gB += 32;                                                           \
  } while (0)

  // prologue: fill slots 0..2 (12 loads/thread outstanding)
  STAGE_T(0);
  STAGE_T(1);
  STAGE_T(2);

  for (int t = 0; t < NT; ++t) {
    const int rem = NT - 1 - t;
    // ensure tile t landed; keep tiles t+1,t+2 (8 loads) in flight
    if (rem >= 2)      asm volatile("s_waitcnt vmcnt(8)" ::: "memory");
    else if (rem == 1) asm volatile("s_waitcnt vmcnt(4)" ::: "memory");
    else               asm volatile("s_waitcnt vmcnt(0)" ::: "memory");
    __builtin_amdgcn_s_barrier();
    asm volatile("" ::: "memory");          // no memory op hoists above barrier
    __builtin_amdgcn_sched_barrier(0);      // pin region start

    if (t + 3 < NT) { STAGE_T((t + 3) & 3); }  // slot freed by tile t-1 (reads done, see below)

    const unsigned short* sA = smem + ((t & 3) << 14);
    const unsigned short* sB = sA + 8192;
    bf16x8 af[8], bfr[4];
#pragma unroll
    for (int mi = 0; mi < 8; mi++)
      af[mi] = *(const bf16x8*)&sA[aoff + mi * 512];
#pragma unroll
    for (int ni = 0; ni < 4; ni++)
      bfr[ni] = *(const bf16x8*)&sB[boff + ni * 512];

    __builtin_amdgcn_s_setprio(1);
#pragma unroll
    for (int mi = 0; mi < 8; mi++)
#pragma unroll
      for (int ni = 0; ni < 4; ni++)
        acc[mi][ni] = __builtin_amdgcn_mfma_f32_16x16x32_bf16(af[mi], bfr[ni], acc[mi][ni], 0, 0, 0);
    __builtin_amdgcn_s_setprio(0);
    // Pin: MFMAs (and their lgkmcnt waits => ds_read completion) retire before
    // the next iteration's barrier. Closes the WAR window on the reuse slot.
    __builtin_amdgcn_sched_barrier(0);
  }
#undef STAGE_T

  // epilogue: C/D layout col = lane&15, row = quad*4 + reg (m89-verified)
  const int row0 = m0 + wr + quad * 4;
  const int col0 = n0 + wc + l16;
#pragma unroll
  for (int mi = 0; mi < 8; mi++) {
#pragma unroll
    for (int r = 0; r < 4; r++) {
      const int row = row0 + mi * 16 + r;
#pragma unroll
      for (int ni = 0; ni < 4; ni++) {
        const int col = col0 + ni * 16;
        float v = acc[mi][ni][r];
        if (MODE == 0) {
          H[(size_t)row * ldh + col] = f2b(v);
        } else if (MODE == 1) {
          const size_t idx = (size_t)row * ldh + col;
          float u = b2f(H[idx]);
          float g = v / (1.0f + __expf(-v));   // silu
          H[idx] = f2b(g * u);
        } else {
          Out[(size_t)row * ldh + col] = v;
        }
      }
    }
  }
}

// ---------------- launcher ----------------

extern "C" void kernel_launch(void* const* d_in, const int* in_sizes, int n_in,
                              void* d_out, int out_size, void* d_ws, size_t ws_size,
                              hipStream_t stream) {
  const float* x      = (const float*)d_in[0];
  const float* tw     = (const float*)d_in[1];
  const float* w1     = (const float*)d_in[2];   // gate [DIM, HID]
  const float* w3     = (const float*)d_in[3];   // up   [DIM, HID]
  const float* w2     = (const float*)d_in[4];   // down [HID, DIM]
  const float* a_up   = (const float*)d_in[5];
  const float* b_up   = (const float*)d_in[6];
  const float* a_gate = (const float*)d_in[7];
  const float* b_gate = (const float*)d_in[8];
  const float* a_down = (const float*)d_in[9];
  const float* b_down = (const float*)d_in[10];

  // workspace layout (bf16 elements)
  unsigned short* Xa   = (unsigned short*)d_ws;                 // [8192][4160]
  unsigned short* BupT = Xa + (size_t)MTOK * KP1;               // [11008][4160]
  unsigned short* BgT  = BupT + (size_t)HIDD * KP1;             // [11008][4160]
  unsigned short* BdT  = BgT + (size_t)HIDD * KP1;              // [4096][11072]
  unsigned short* Ha   = BdT + (size_t)DIMD * KP2;              // [8192][11072]
  size_t need = ((size_t)MTOK * KP1 + 2 * (size_t)HIDD * KP1 +
                 (size_t)DIMD * KP2 + (size_t)MTOK * KP2) * 2;
  if (ws_size < need) return;  // insufficient workspace: fail cleanly

  build_xaug<<<MTOK, 256, 0, stream>>>(x, tw, a_up, a_gate, Xa);
  build_baug<<<dim3(KP1 / 64, HIDD / 64), 256, 0, stream>>>(w3, b_up, BupT, HIDD, DIMD, 4096, KP1);
  build_baug<<<dim3(KP1 / 64, HIDD / 64), 256, 0, stream>>>(w1, b_gate, BgT, HIDD, DIMD, 4104, KP1);
  build_baug<<<dim3(KP2 / 64, DIMD / 64), 256, 0, stream>>>(w2, b_down, BdT, DIMD, HIDD, 11008, KP2);

  // up: Ha[m][n] = bf16(X_aug @ B_up_aug)
  gemm_ring<0><<<dim3(HIDD / 256, MTOK / 256), 512, 0, stream>>>(Xa, BupT, Ha, nullptr, KP1, KP1, KP1, KP2);
  // gate + swiglu: Ha[m][n] = bf16(silu(X_aug @ B_gate_aug) * Ha[m][n])
  gemm_ring<1><<<dim3(HIDD / 256, MTOK / 256), 512, 0, stream>>>(Xa, BgT, Ha, nullptr, KP1, KP1, KP1, KP2);
  // ha_down into Ha cols 11008..11071
  lora_down_k<<<MTOK, 256, 0, stream>>>(Ha, a_down, tw);
  // down: out = fp32(H_aug @ B_down_aug)
  gemm_ring<2><<<dim3(DIMD / 256, MTOK / 256), 512, 0, stream>>>(Ha, BdT, nullptr, (float*)d_out, KP2, KP2, KP2, DIMD);
}